// Round 7
// baseline (220.276 us; speedup 1.0000x reference)
//
#include <hip/hip_runtime.h>
#include <hip/hip_bf16.h>
#include <math.h>

// Problem dims (fixed by reference)
#define N_ROWS 8192
#define D_IN   2048
#define D_H    512
#define D_OUTF 128

typedef __attribute__((ext_vector_type(8))) short bf16x8;
typedef __attribute__((ext_vector_type(4))) float f32x4;

enum { EPI_H0B = 0, EPI_BIASB = 1, EPI_A12 = 2, EPI_ZW = 3, EPI_C3RES = 4 };

__device__ __forceinline__ short f2bf(float f) {
    unsigned u = __builtin_bit_cast(unsigned, f);
    u += 0x7fffu + ((u >> 16) & 1u);          // RNE to bf16
    return (short)(u >> 16);
}
__device__ __forceinline__ float bf2f(short h) {
    unsigned u = ((unsigned)(unsigned short)h) << 16;
    return __builtin_bit_cast(float, u);
}

// global -> LDS direct (16B/lane). Dest must be wave-uniform base; HW adds lane*16.
#define GLOAD16(gsrc, ldst) \
    __builtin_amdgcn_global_load_lds( \
        (const __attribute__((address_space(1))) void*)(gsrc), \
        (__attribute__((address_space(3))) void*)(ldst), 16, 0, 0)

// Weight/activation scratch layout (short-element offsets into the mam region).
// All scratch ends at byte 25.2MB -> mam rows >= 1024 (byte >= 32MB) are always safe.
constexpr size_t OFF_P1T  = 0;          // [512][2048]
constexpr size_t OFF_P2T  = 1048576;    // [512][512]
constexpr size_t OFF_A1T  = 1310720;
constexpr size_t OFF_A2T  = 1572864;
constexpr size_t OFF_C1T  = 1835008;
constexpr size_t OFF_C2T  = 2097152;
constexpr size_t OFF_C3T  = 2359296;    // [128][512]
constexpr size_t OFF_REST = 2424832;    // [128][512]
constexpr size_t OFF_SLOT1 = 4194304;   // bf16 [8192][512] activation slot
constexpr size_t OFF_SLOT2 = 8388608;   // bf16 [8192][512] activation slot

// mam slice writer: rows [mrow0, mrow0+mrows), nmb blocks of 256 threads
__device__ __forceinline__ void mam_slice(const float* __restrict__ s,
                                          float* __restrict__ mam_out,
                                          int mrow0, int mrows, int mb, int nmb)
{
    const f32x4* s4 = (const f32x4*)s;
    const size_t total  = (size_t)mrows * 2048;        // float4 per row = 2048
    const size_t stride = (size_t)nmb * 256;
    for (size_t gg = (size_t)mb * 256 + threadIdx.x; gg < total; gg += stride) {
        const int row = mrow0 + (int)(gg >> 11);
        const int c4  = (int)(gg & 2047);
        f32x4 o = s[row] * s4[c4];
        __builtin_nontemporal_store(o, (f32x4*)(mam_out + ((size_t)row << 13) + ((size_t)c4 << 2)));
    }
}

// ---------------------------------------------------------------------------
// Batched weight transpose+convert: W[K][N] f32 -> Wt[N][K] bf16, 32x32 tiles.
// blockIdx.y == 8 lane zeroes out_aw (must precede a12's atomics).
// ---------------------------------------------------------------------------
__global__ __launch_bounds__(256)
void wtrans(const float* __restrict__ p1, const float* __restrict__ p2,
            const float* __restrict__ a1, const float* __restrict__ a2,
            const float* __restrict__ c1, const float* __restrict__ c2,
            const float* __restrict__ c3, const float* __restrict__ rs,
            short* __restrict__ z, float* __restrict__ aw0)
{
    __shared__ float t[32][33];
    const int w = blockIdx.y;
    const int tile = blockIdx.x;
    if (w == 8) {                       // zero aw accumulator
        int i = tile * 256 + threadIdx.y * 32 + threadIdx.x;
        if (i < N_ROWS) aw0[i] = 0.f;
        return;
    }
    const float* src; short* dst; int Kw, Nw;
    switch (w) {
        case 0: src = p1; dst = z + OFF_P1T;  Kw = 2048; Nw = 512; break;
        case 1: src = p2; dst = z + OFF_P2T;  Kw = 512;  Nw = 512; break;
        case 2: src = a1; dst = z + OFF_A1T;  Kw = 512;  Nw = 512; break;
        case 3: src = a2; dst = z + OFF_A2T;  Kw = 512;  Nw = 512; break;
        case 4: src = c1; dst = z + OFF_C1T;  Kw = 512;  Nw = 512; break;
        case 5: src = c2; dst = z + OFF_C2T;  Kw = 512;  Nw = 512; break;
        case 6: src = c3; dst = z + OFF_C3T;  Kw = 512;  Nw = 128; break;
        default: src = rs; dst = z + OFF_REST; Kw = 512; Nw = 128; break;
    }
    const int txc = Nw >> 5, tyc = Kw >> 5;
    if (tile >= txc * tyc) return;
    const int tc = tile % txc, tr = tile / txc;
    const int x = threadIdx.x, y = threadIdx.y;
    #pragma unroll
    for (int j = 0; j < 4; ++j)
        t[y + 8 * j][x] = src[(size_t)(tr * 32 + y + 8 * j) * Nw + tc * 32 + x];
    __syncthreads();
    #pragma unroll
    for (int j = 0; j < 4; ++j)
        dst[(size_t)(tc * 32 + y + 8 * j) * Kw + tr * 32 + x] = f2bf(t[x][y + 8 * j]);
}

// ---------------------------------------------------------------------------
// bf16 MFMA GEMM: BM=64, BN=128, BK=64, 256 thr = 4 waves (2x2), wave tile
// 32x64. A: [M][K] f32 (reg-staged) or bf16 (global_load_lds); B/B2: [N][K]
// bf16 k-major. GEMM planes are blockIdx.y < 128; planes >= 128 stream a mam
// slice (overlaps latency-bound GEMM with the pure-BW outer-product write).
// ---------------------------------------------------------------------------
template<bool AF32, bool DUALB, int EPI, int KT>
__global__ __launch_bounds__(256)
void gemm(const void* __restrict__ Ap, const short* __restrict__ Bt,
          const short* __restrict__ Bt2,
          const float* __restrict__ bias, const float* __restrict__ bias2,
          const float* __restrict__ sb,
          const float* __restrict__ auxw, float* __restrict__ auxo,
          float* __restrict__ C, float* __restrict__ C2,
          short* __restrict__ Cb, int N,
          const float* __restrict__ s_mam, float* __restrict__ mam_out,
          int mrow0, int mrows)
{
    constexpr int NSTEP = KT / 64;
    constexpr int BROWS = DUALB ? 256 : 128;
    __shared__ short lds_a[2][64 * 64];
    __shared__ short lds_b[2][BROWS * 64];
    const int tid = threadIdx.x;
    const int gx  = gridDim.x;
    if (blockIdx.y >= 128) {            // mam overlap plane
        const int mb  = (blockIdx.y - 128) * gx + blockIdx.x;
        const int nmb = (gridDim.y - 128) * gx;
        mam_slice(s_mam, mam_out, mrow0, mrows, mb, nmb);
        return;
    }
    // XCD-aware swizzle over the 128*gx GEMM planes (multiple of 8)
    const int orig = blockIdx.y * gx + blockIdx.x;
    const int cpx  = (gx * 128) >> 3;
    const int wg   = (orig & 7) * cpx + (orig >> 3);
    const int bx   = wg % gx;
    const int by   = wg / gx;
    const int row0 = by * 64;
    const int col0 = bx * 128;
    const int lane = tid & 63;
    const int wid  = tid >> 6;
    const int wm   = (wid >> 1) * 32;
    const int wn   = (wid & 1) * 64;
    const int l15  = lane & 15;
    const int lhi  = lane >> 4;

    f32x4 acc[2][4], acc2[2][4];
    #pragma unroll
    for (int i = 0; i < 2; ++i)
        #pragma unroll
        for (int j = 0; j < 4; ++j) {
            f32x4 z = {0.f, 0.f, 0.f, 0.f};
            acc[i][j] = z;
            if constexpr (DUALB) acc2[i][j] = z;
        }

    auto do_compute = [&](int p) {
        const short* la = lds_a[p];
        const short* lb = lds_b[p];
        #pragma unroll
        for (int kk = 0; kk < 2; ++kk) {
            bf16x8 af[2], bfr[4], bfr2[4];
            #pragma unroll
            for (int mi = 0; mi < 2; ++mi) {
                const int row = wm + mi * 16 + l15;
                af[mi] = *(const bf16x8*)(la + row * 64 + (((kk * 4 + lhi) ^ (row & 7)) << 3));
            }
            #pragma unroll
            for (int ni = 0; ni < 4; ++ni) {
                const int row = wn + ni * 16 + l15;
                bfr[ni] = *(const bf16x8*)(lb + row * 64 + (((kk * 4 + lhi) ^ (row & 7)) << 3));
                if constexpr (DUALB)
                    bfr2[ni] = *(const bf16x8*)(lb + (row + 128) * 64 + (((kk * 4 + lhi) ^ (row & 7)) << 3));
            }
            #pragma unroll
            for (int mi = 0; mi < 2; ++mi)
                #pragma unroll
                for (int ni = 0; ni < 4; ++ni) {
                    acc[mi][ni] = __builtin_amdgcn_mfma_f32_16x16x32_bf16(
                        af[mi], bfr[ni], acc[mi][ni], 0, 0, 0);
                    if constexpr (DUALB)
                        acc2[mi][ni] = __builtin_amdgcn_mfma_f32_16x16x32_bf16(
                            af[mi], bfr2[ni], acc2[mi][ni], 0, 0, 0);
                }
        }
    };

    if constexpr (!AF32) {
        // ---- async gload_lds path (A is bf16 k-major) ----
        auto stage = [&](int p, int kt) {
            #pragma unroll
            for (int i = 0; i < 2; ++i) {
                const int q = tid + (i << 8);
                const int r = q >> 3, c16 = q & 7;
                GLOAD16((const short*)Ap + (size_t)(row0 + r) * KT + kt + ((c16 ^ (r & 7)) << 3),
                        lds_a[p] + (i << 11) + (wid << 9));
            }
            #pragma unroll
            for (int i = 0; i < 4; ++i) {
                const int q = tid + (i << 8);
                const int r = q >> 3, c16 = q & 7;
                GLOAD16(Bt + (size_t)(col0 + r) * KT + kt + ((c16 ^ (r & 7)) << 3),
                        lds_b[p] + (i << 11) + (wid << 9));
                if constexpr (DUALB)
                    GLOAD16(Bt2 + (size_t)(col0 + r) * KT + kt + ((c16 ^ (r & 7)) << 3),
                            lds_b[p] + 8192 + (i << 11) + (wid << 9));
            }
        };
        stage(0, 0);
        if (NSTEP > 1) stage(1, 64);
        for (int s = 0; s < NSTEP; ++s) {
            if (s + 1 < NSTEP) {            // tile s done; tile s+1 stays in flight
                if constexpr (DUALB) asm volatile("s_waitcnt vmcnt(10)" ::: "memory");
                else                 asm volatile("s_waitcnt vmcnt(6)"  ::: "memory");
            } else {
                asm volatile("s_waitcnt vmcnt(0)" ::: "memory");
            }
            __builtin_amdgcn_s_barrier();           // all waves' tile-s parts done
            __builtin_amdgcn_sched_barrier(0);
            do_compute(s & 1);
            __builtin_amdgcn_s_barrier();           // all done reading buf[s&1]
            __builtin_amdgcn_sched_barrier(0);
            if (s + 2 < NSTEP) stage(s & 1, (s + 2) * 64);
        }
    } else {
        // ---- reg-staged path (A is f32, converted in flight) ----
        bf16x8 ra[2], rb[4];
        auto load_a = [&](int kt) {
            #pragma unroll
            for (int i = 0; i < 2; ++i) {
                const int q = tid + (i << 8);
                const int r = q >> 3, c16 = q & 7;
                const float* p = (const float*)Ap + (size_t)(row0 + r) * KT + kt + c16 * 8;
                float4 u0 = *(const float4*)p;
                float4 u1 = *(const float4*)(p + 4);
                bf16x8 v;
                v[0] = f2bf(u0.x); v[1] = f2bf(u0.y); v[2] = f2bf(u0.z); v[3] = f2bf(u0.w);
                v[4] = f2bf(u1.x); v[5] = f2bf(u1.y); v[6] = f2bf(u1.z); v[7] = f2bf(u1.w);
                ra[i] = v;
            }
        };
        auto load_b = [&](int kt) {
            #pragma unroll
            for (int i = 0; i < 4; ++i) {
                const int q = tid + (i << 8);
                const int r = q >> 3, c16 = q & 7;
                rb[i] = *(const bf16x8*)(Bt + (size_t)(col0 + r) * KT + kt + c16 * 8);
            }
        };
        auto write_tile = [&](int p) {
            #pragma unroll
            for (int i = 0; i < 2; ++i) {
                const int q = tid + (i << 8);
                const int r = q >> 3, c16 = q & 7;
                *(bf16x8*)(lds_a[p] + r * 64 + ((c16 ^ (r & 7)) << 3)) = ra[i];
            }
            #pragma unroll
            for (int i = 0; i < 4; ++i) {
                const int q = tid + (i << 8);
                const int r = q >> 3, c16 = q & 7;
                *(bf16x8*)(lds_b[p] + r * 64 + ((c16 ^ (r & 7)) << 3)) = rb[i];
            }
        };
        load_a(0); load_b(0);
        write_tile(0);
        if (NSTEP > 1) { load_a(64); load_b(64); }
        #pragma unroll 2
        for (int s = 0; s < NSTEP; ++s) {
            __syncthreads();
            do_compute(s & 1);
            if (s + 1 < NSTEP) {
                write_tile((s + 1) & 1);
                if (s + 2 < NSTEP) { load_a((s + 2) * 64); load_b((s + 2) * 64); }
            }
        }
    }

    // epilogues: C/D row=(lane>>4)*4+j, col=lane&15 [verified rounds 1-6]
    if constexpr (EPI == EPI_A12) {
        float pd[2][4];
        #pragma unroll
        for (int mi = 0; mi < 2; ++mi)
            #pragma unroll
            for (int j = 0; j < 4; ++j) pd[mi][j] = 0.f;
        #pragma unroll
        for (int mi = 0; mi < 2; ++mi)
            #pragma unroll
            for (int ni = 0; ni < 4; ++ni) {
                const int col = col0 + wn + ni * 16 + l15;
                const float b1 = bias[col], b2 = bias2[col], w3 = auxw[col];
                #pragma unroll
                for (int j = 0; j < 4; ++j) {
                    float g1 = 1.f / (1.f + expf(-(acc[mi][ni][j] + b1)));
                    float g2 = tanhf(acc2[mi][ni][j] + b2);
                    pd[mi][j] += g1 * g2 * w3;
                }
            }
        #pragma unroll
        for (int mi = 0; mi < 2; ++mi)
            #pragma unroll
            for (int j = 0; j < 4; ++j) {
                float v = pd[mi][j];
                v += __shfl_xor(v, 1); v += __shfl_xor(v, 2);
                v += __shfl_xor(v, 4); v += __shfl_xor(v, 8);
                if (l15 == 0) {
                    if (bx == 0 && wn == 0) v += sb[0];   // fold a3_b exactly once/row
                    atomicAdd(&auxo[row0 + wm + mi * 16 + lhi * 4 + j], v);
                }
            }
    } else if constexpr (EPI == EPI_ZW) {
        // Cb = bf16(acc); t[col] += sum_rows u[row]*acc  (colsum fused, fp32-exact)
        float ur[2][4];
        #pragma unroll
        for (int mi = 0; mi < 2; ++mi)
            #pragma unroll
            for (int j = 0; j < 4; ++j)
                ur[mi][j] = auxw[row0 + wm + mi * 16 + lhi * 4 + j];
        float tp[4] = {0.f, 0.f, 0.f, 0.f};
        #pragma unroll
        for (int mi = 0; mi < 2; ++mi)
            #pragma unroll
            for (int ni = 0; ni < 4; ++ni) {
                const int col = col0 + wn + ni * 16 + l15;
                #pragma unroll
                for (int j = 0; j < 4; ++j) {
                    const int row = row0 + wm + mi * 16 + lhi * 4 + j;
                    const float val = acc[mi][ni][j];
                    Cb[(size_t)row * N + col] = f2bf(val);
                    tp[ni] += ur[mi][j] * val;
                }
            }
        #pragma unroll
        for (int ni = 0; ni < 4; ++ni) {
            float v = tp[ni];
            v += __shfl_xor(v, 16); v += __shfl_xor(v, 32);
            if (lhi == 0)
                atomicAdd(&auxo[col0 + wn + ni * 16 + l15], v);
        }
    } else if constexpr (EPI == EPI_C3RES) {
        if (bx == 0) {
            float ur[2][4];
            #pragma unroll
            for (int mi = 0; mi < 2; ++mi)
                #pragma unroll
                for (int j = 0; j < 4; ++j)
                    ur[mi][j] = auxw[row0 + wm + mi * 16 + lhi * 4 + j];
            float tp[4] = {0.f, 0.f, 0.f, 0.f};
            #pragma unroll
            for (int mi = 0; mi < 2; ++mi)
                #pragma unroll
                for (int ni = 0; ni < 4; ++ni) {
                    const int c = wn + ni * 16 + l15;
                    #pragma unroll
                    for (int j = 0; j < 4; ++j) {
                        const int row = row0 + wm + mi * 16 + lhi * 4 + j;
                        const float val = acc[mi][ni][j];
                        C[(size_t)row * D_OUTF + c] = val;
                        tp[ni] += ur[mi][j] * val;
                    }
                }
            #pragma unroll
            for (int ni = 0; ni < 4; ++ni) {
                float v = tp[ni];
                v += __shfl_xor(v, 16); v += __shfl_xor(v, 32);
                if (lhi == 0)
                    atomicAdd(&auxo[wn + ni * 16 + l15], v);
            }
        } else {
            #pragma unroll
            for (int mi = 0; mi < 2; ++mi)
                #pragma unroll
                for (int ni = 0; ni < 4; ++ni) {
                    const int c = wn + ni * 16 + l15;
                    #pragma unroll
                    for (int j = 0; j < 4; ++j) {
                        const int row = row0 + wm + mi * 16 + lhi * 4 + j;
                        C2[(size_t)row * D_OUTF + c] = acc[mi][ni][j] + bias[c];
                    }
                }
        }
    } else {
        #pragma unroll
        for (int mi = 0; mi < 2; ++mi)
            #pragma unroll
            for (int ni = 0; ni < 4; ++ni) {
                const int col = col0 + wn + ni * 16 + l15;
                #pragma unroll
                for (int j = 0; j < 4; ++j) {
                    const int row = row0 + wm + mi * 16 + lhi * 4 + j;
                    float val = acc[mi][ni][j] + bias[col];
                    if constexpr (EPI == EPI_H0B) val = fmaxf(val, 0.f);
                    Cb[(size_t)row * N + col] = f2bf(val);
                }
            }
    }
}

// ---------------------------------------------------------------------------
template<int NT>
__device__ __forceinline__ void block_reduce2(float& s, float& s2)
{
    #pragma unroll
    for (int o = 32; o > 0; o >>= 1) {
        s  += __shfl_down(s,  o);
        s2 += __shfl_down(s2, o);
    }
    __shared__ float sm[2][NT / 64];
    const int wid  = threadIdx.x >> 6;
    const int lane = threadIdx.x & 63;
    if (lane == 0) { sm[0][wid] = s; sm[1][wid] = s2; }
    __syncthreads();
    float a = 0.f, b = 0.f;
    #pragma unroll
    for (int w = 0; w < NT / 64; ++w) { a += sm[0][w]; b += sm[1][w]; }
    s = a; s2 = b;
}

// LayerNorm, wave-per-row (4 rows/block, shfl-only): bf16 in -> bf16 out
__global__ __launch_bounds__(256)
void ln_b(const short* __restrict__ in, const float* __restrict__ g,
          const float* __restrict__ b, short* __restrict__ out)
{
    const int row  = blockIdx.x * 4 + (threadIdx.x >> 6);
    const int lane = threadIdx.x & 63;
    const int c0   = lane * 8;
    bf16x8 h8 = *(const bf16x8*)(in + (size_t)row * D_H + c0);
    float v[8], s = 0.f, s2 = 0.f;
    #pragma unroll
    for (int i = 0; i < 8; ++i) { v[i] = bf2f(h8[i]); s += v[i]; s2 += v[i] * v[i]; }
    #pragma unroll
    for (int o = 1; o < 64; o <<= 1) { s += __shfl_xor(s, o); s2 += __shfl_xor(s2, o); }
    const float mean = s * (1.f / D_H);
    const float rs   = rsqrtf(s2 * (1.f / D_H) - mean * mean + 1e-5f);
    float ga[8], ba[8];
    *(float4*)ga       = *(const float4*)(g + c0);
    *(float4*)(ga + 4) = *(const float4*)(g + c0 + 4);
    *(float4*)ba       = *(const float4*)(b + c0);
    *(float4*)(ba + 4) = *(const float4*)(b + c0 + 4);
    bf16x8 o8;
    #pragma unroll
    for (int i = 0; i < 8; ++i) o8[i] = f2bf((v[i] - mean) * rs * ga[i] + ba[i]);
    *(bf16x8*)(out + (size_t)row * D_H + c0) = o8;
}

// x_next = LN(relu(u_i*t + v_i*zw_i + cb))*g + b + resid ; wave-per-row, bf16
__global__ __launch_bounds__(256)
void fuse_b(const short* __restrict__ zw, const float* __restrict__ t,
            const float* __restrict__ u, const float* __restrict__ vv,
            const float* __restrict__ cb, const float* __restrict__ g,
            const float* __restrict__ b, const short* __restrict__ resid,
            short* __restrict__ out)
{
    const int row  = blockIdx.x * 4 + (threadIdx.x >> 6);
    const int lane = threadIdx.x & 63;
    const int c0   = lane * 8;
    const float ui = u[row], vi = vv[row];
    bf16x8 z8 = *(const bf16x8*)(zw + (size_t)row * D_H + c0);
    float ta[8], ca[8];
    *(float4*)ta       = *(const float4*)(t + c0);
    *(float4*)(ta + 4) = *(const float4*)(t + c0 + 4);
    *(float4*)ca       = *(const float4*)(cb + c0);
    *(float4*)(ca + 4) = *(const float4*)(cb + c0 + 4);
    float y[8], s = 0.f, s2 = 0.f;
    #pragma unroll
    for (int i = 0; i < 8; ++i) {
        float val = fmaxf(ui * ta[i] + vi * bf2f(z8[i]) + ca[i], 0.f);
        y[i] = val; s += val; s2 += val * val;
    }
    #pragma unroll
    for (int o = 1; o < 64; o <<= 1) { s += __shfl_xor(s, o); s2 += __shfl_xor(s2, o); }
    const float mean = s * (1.f / D_H);
    const float rs   = rsqrtf(s2 * (1.f / D_H) - mean * mean + 1e-5f);
    bf16x8 r8 = *(const bf16x8*)(resid + (size_t)row * D_H + c0);
    float ga[8], ba[8];
    *(float4*)ga       = *(const float4*)(g + c0);
    *(float4*)(ga + 4) = *(const float4*)(g + c0 + 4);
    *(float4*)ba       = *(const float4*)(b + c0);
    *(float4*)(ba + 4) = *(const float4*)(b + c0 + 4);
    bf16x8 o8;
    #pragma unroll
    for (int i = 0; i < 8; ++i)
        o8[i] = f2bf((y[i] - mean) * rs * ga[i] + ba[i] + bf2f(r8[i]));
    *(bf16x8*)(out + (size_t)row * D_H + c0) = o8;
}

// s = sigmoid(aw); S = sum(s); u = s*dinv; v = dinv^2*(1-s^2); zero t1..t3
__global__ __launch_bounds__(1024)
void prep(const float* __restrict__ aw, float* __restrict__ s_out,
          float* __restrict__ u, float* __restrict__ v,
          float* __restrict__ t1, float* __restrict__ t2, float* __restrict__ t3)
{
    const int tid = threadIdx.x;
    float acc = 0.f;
    for (int i = tid; i < N_ROWS; i += 1024) {
        float si = 1.f / (1.f + expf(-aw[i]));
        s_out[i] = si;
        acc += si;
    }
    float dummy = 0.f;
    block_reduce2<1024>(acc, dummy);
    const float S = acc;
    for (int i = tid; i < N_ROWS; i += 1024) {
        float si   = s_out[i];
        float dinv = rsqrtf(1.f + si * (S - si));   // deg = 1 + s_i*(S - s_i)
        u[i] = si * dinv;
        v[i] = dinv * dinv * (1.f - si * si);
    }
    if (tid < D_H)   { t1[tid] = 0.f; t2[tid] = 0.f; }
    if (tid < D_OUTF)  t3[tid] = 0.f;
}

// ---------------------------------------------------------------------------
// tail: blocks 0..2047 layer-3 fuse; blocks 2048..4095 mam rows 0-1023 and
// 6656-8191 (scratch region rows 0-1023 are dead by now).
// ---------------------------------------------------------------------------
__global__ __launch_bounds__(256)
void tail(const float* __restrict__ zw, const float* __restrict__ t,
          const float* __restrict__ u, const float* __restrict__ vv,
          const float* __restrict__ cb, const float* __restrict__ g,
          const float* __restrict__ b, const float* __restrict__ resid,
          float* __restrict__ out,
          const float* __restrict__ s, float* __restrict__ mam_out)
{
    if (blockIdx.x < 2048) {
        const int row  = blockIdx.x * 4 + (threadIdx.x >> 6);
        const int lane = threadIdx.x & 63;
        const int c0   = lane * 2;
        const float ui = u[row], vi = vv[row];
        float2 z2 = *(const float2*)(zw + (size_t)row * D_OUTF + c0);
        float y0 = fmaxf(ui * t[c0]     + vi * z2.x + cb[c0],     0.f);
        float y1 = fmaxf(ui * t[c0 + 1] + vi * z2.y + cb[c0 + 1], 0.f);
        float sr = y0 + y1, s2 = y0 * y0 + y1 * y1;
        #pragma unroll
        for (int o = 1; o < 64; o <<= 1) { sr += __shfl_xor(sr, o); s2 += __shfl_xor(s2, o); }
        const float mean = sr * (1.f / D_OUTF);
        const float rs   = rsqrtf(s2 * (1.f / D_OUTF) - mean * mean + 1e-5f);
        float2 r2 = *(const float2*)(resid + (size_t)row * D_OUTF + c0);
        float2 o2;
        o2.x = (y0 - mean) * rs * g[c0]     + b[c0]     + r2.x;
        o2.y = (y1 - mean) * rs * g[c0 + 1] + b[c0 + 1] + r2.y;
        *(float2*)(out + (size_t)row * D_OUTF + c0) = o2;
        return;
    }
    // mam rows 0..1023 and 6656..8191 (2560 rows)
    const int mb = blockIdx.x - 2048;
    const f32x4* s4 = (const f32x4*)s;
    const size_t total  = (size_t)2560 * 2048;
    const size_t stride = (size_t)2048 * 256;
    for (size_t gg = (size_t)mb * 256 + threadIdx.x; gg < total; gg += stride) {
        int ri = (int)(gg >> 11);
        const int row = ri < 1024 ? ri : 6656 + (ri - 1024);
        const int c4  = (int)(gg & 2047);
        f32x4 o = s[row] * s4[c4];
        __builtin_nontemporal_store(o, (f32x4*)(mam_out + ((size_t)row << 13) + ((size_t)c4 << 2)));
    }
}

// ---------------------------------------------------------------------------
// ws: h0b bf16 8MB | zwb bf16 8MB | zw3 4MB | resb 4MB | smalls. Weights and
// slot1/slot2 live in the mam output region (first 25.2MB = rows < 1024);
// mam rows >= 1024 are streamed early inside the post-prep GEMMs, rows < 1024
// plus the remainder in tail.
// ---------------------------------------------------------------------------
extern "C" void kernel_launch(void* const* d_in, const int* in_sizes, int n_in,
                              void* d_out, int out_size, void* d_ws, size_t ws_size,
                              hipStream_t stream)
{
    const float* x     = (const float*)d_in[0];
    const float* p1_w  = (const float*)d_in[1];
    const float* p1_b  = (const float*)d_in[2];
    const float* ln0_g = (const float*)d_in[3];
    const float* ln0_b = (const float*)d_in[4];
    const float* p2_w  = (const float*)d_in[5];
    const float* p2_b  = (const float*)d_in[6];
    const float* a1_w  = (const float*)d_in[7];
    const float* a1_b  = (const float*)d_in[8];
    const float* a2_w  = (const float*)d_in[9];
    const float* a2_b  = (const float*)d_in[10];
    const float* a3_w  = (const float*)d_in[11];
    const float* a3_b  = (const float*)d_in[12];
    const float* c1_w  = (const float*)d_in[13];
    const float* c1_b  = (const float*)d_in[14];
    const float* ln1_g = (const float*)d_in[15];
    const float* ln1_b = (const float*)d_in[16];
    const float* c2_w  = (const float*)d_in[17];
    const float* c2_b  = (const float*)d_in[18];
    const float* ln2_g = (const float*)d_in[19];
    const float* ln2_b = (const float*)d_in[20];
    const float* c3_w  = (const float*)d_in[21];
    const float* c3_b  = (const float*)d_in[22];
    const float* ln3_g = (const float*)d_in[23];
    const float* ln3_b = (const float*)d_in[24];
    const float* res_w = (const float*)d_in[25];
    const float* res_b = (const float*)d_in[26];

    float* ws   = (float*)d_ws;
    short* wsS  = (short*)d_ws;
    short* h0b  = wsS;                                 // bf16 [8192][512]
    short* zwb  = wsS + (size_t)N_ROWS * D_H;          // bf16 [8192][512]
    float* wsF  = ws + (size_t)N_ROWS * D_H / 2 * 2;   // after the two bf16 slots
    float* zw3  = wsF;                                 // [8192][128] f32
    float* resb = zw3 + (size_t)N_ROWS * D_OUTF;       // [8192][128] f32
    float* s_buf = resb + (size_t)N_ROWS * D_OUTF;
    float* u_buf = s_buf + N_ROWS;
    float* v_buf = u_buf + N_ROWS;
    float* t1    = v_buf + N_ROWS;
    float* t2    = t1 + D_H;
    float* t3    = t2 + D_H;

    float* out_x3  = (float*)d_out;
    float* out_aw  = out_x3 + (size_t)N_ROWS * D_OUTF;
    float* out_mam = out_aw + N_ROWS;
    short* Z     = (short*)out_mam;                    // scratch in mam region
    short* slot1 = Z + OFF_SLOT1;                      // h_ln -> x1
    short* slot2 = Z + OFF_SLOT2;                      // h    -> x2

    dim3 blk(256);
    dim3 tb(32, 8);
    dim3 gP(4, 128);       // proj / p2 / a12: GEMM planes only
    dim3 gZ(4, 128 + 32);  // zw1/zw2: + 128 mam blocks
    dim3 gC(2, 128 + 64);  // c3res:   + 128 mam blocks

    wtrans<<<dim3(1024, 9), tb, 0, stream>>>(p1_w, p2_w, a1_w, a2_w, c1_w, c2_w, c3_w, res_w, Z, out_aw);

    // projection (reg-staged f32 A path)
    gemm<true,  false, EPI_H0B,   D_IN><<<gP, blk, 0, stream>>>(
        x, Z + OFF_P1T, nullptr, p1_b, nullptr, nullptr, nullptr, nullptr, nullptr, nullptr, h0b, D_H,
        nullptr, nullptr, 0, 0);
    ln_b<<<2048, 256, 0, stream>>>(h0b, ln0_g, ln0_b, slot1);
    gemm<false, false, EPI_BIASB, D_H><<<gP, blk, 0, stream>>>(
        slot1, Z + OFF_P2T, nullptr, p2_b, nullptr, nullptr, nullptr, nullptr, nullptr, nullptr, slot2, D_H,
        nullptr, nullptr, 0, 0);
    // attention gate: aw = (sigmoid(h@a1+b1)*tanh(h@a2+b2))@a3_w + a3_b
    gemm<false, true,  EPI_A12,   D_H><<<gP, blk, 0, stream>>>(
        slot2, Z + OFF_A1T, Z + OFF_A2T, a1_b, a2_b, a3_b, a3_w, out_aw, nullptr, nullptr, nullptr, D_H,
        nullptr, nullptr, 0, 0);
    prep<<<1, 1024, 0, stream>>>(out_aw, s_buf, u_buf, v_buf, t1, t2, t3);
    // GCN layer 1  (+ mam rows 1024-3071)
    gemm<false, false, EPI_ZW,    D_H><<<gZ, blk, 0, stream>>>(
        slot2, Z + OFF_C1T, nullptr, nullptr, nullptr, nullptr, u_buf, t1, nullptr, nullptr, zwb, D_H,
        s_buf, out_mam, 1024, 2048);
    fuse_b<<<2048, 256, 0, stream>>>(zwb, t1, u_buf, v_buf, c1_b, ln1_g, ln1_b, slot2, slot1);
    // GCN layer 2  (+ mam rows 3072-5119)
    gemm<false, false, EPI_ZW,    D_H><<<gZ, blk, 0, stream>>>(
        slot1, Z + OFF_C2T, nullptr, nullptr, nullptr, nullptr, u_buf, t2, nullptr, nullptr, zwb, D_H,
        s_buf, out_mam, 3072, 2048);
    fuse_b<<<2048, 256, 0, stream>>>(zwb, t2, u_buf, v_buf, c2_b, ln2_g, ln2_b, slot1, slot2);
    // GCN layer 3 + residual projection (+ mam rows 5120-6655)
    gemm<false, false, EPI_C3RES, D_H><<<gC, blk, 0, stream>>>(
        slot2, Z + OFF_C3T, nullptr, res_b, nullptr, nullptr, u_buf, t3, zw3, resb, nullptr, 256,
        s_buf, out_mam, 5120, 1536);
    // layer-3 fuse + mam rows 0-1023 & 6656-8191
    tail<<<4096, 256, 0, stream>>>(zw3, t3, u_buf, v_buf, c3_b, ln3_g, ln3_b, resb, out_x3,
                                   s_buf, out_mam);
}

// Round 9
// 186.450 us; speedup vs baseline: 1.1814x; 1.1814x over previous
//
#include <hip/hip_runtime.h>
#include <hip/hip_bf16.h>
#include <math.h>

// Problem dims (fixed by reference)
#define N_ROWS 8192
#define D_IN   2048
#define D_H    512
#define D_OUTF 128

typedef __attribute__((ext_vector_type(8))) short bf16x8;
typedef __attribute__((ext_vector_type(4))) float f32x4;

enum { EPI_H0B = 0, EPI_BIASB = 1, EPI_A12 = 2, EPI_ZW = 3, EPI_C3RES = 4 };

__device__ __forceinline__ short f2bf(float f) {
    unsigned u = __builtin_bit_cast(unsigned, f);
    u += 0x7fffu + ((u >> 16) & 1u);          // RNE to bf16
    return (short)(u >> 16);
}
__device__ __forceinline__ float bf2f(short h) {
    unsigned u = ((unsigned)(unsigned short)h) << 16;
    return __builtin_bit_cast(float, u);
}

// global -> LDS direct (16B/lane). Dest must be wave-uniform base; HW adds lane*16.
#define GLOAD16(gsrc, ldst) \
    __builtin_amdgcn_global_load_lds( \
        (const __attribute__((address_space(1))) void*)(gsrc), \
        (__attribute__((address_space(3))) void*)(ldst), 16, 0, 0)

// Weight/activation scratch layout (short-element offsets into the mam region)
constexpr size_t OFF_P1T  = 0;          // [512][2048]
constexpr size_t OFF_P2T  = 1048576;    // [512][512]
constexpr size_t OFF_A1T  = 1310720;
constexpr size_t OFF_A2T  = 1572864;
constexpr size_t OFF_C1T  = 1835008;
constexpr size_t OFF_C2T  = 2097152;
constexpr size_t OFF_C3T  = 2359296;    // [128][512]
constexpr size_t OFF_REST = 2424832;    // [128][512]
constexpr size_t OFF_SLOT1 = 4194304;   // bf16 [8192][512] activation slot
constexpr size_t OFF_SLOT2 = 8388608;   // bf16 [8192][512] activation slot

// ---------------------------------------------------------------------------
// Batched weight transpose+convert: W[K][N] f32 -> Wt[N][K] bf16, 32x32 tiles.
// blockIdx.y == 8 lane zeroes out_aw (must precede a12's atomics).
// ---------------------------------------------------------------------------
__global__ __launch_bounds__(256)
void wtrans(const float* __restrict__ p1, const float* __restrict__ p2,
            const float* __restrict__ a1, const float* __restrict__ a2,
            const float* __restrict__ c1, const float* __restrict__ c2,
            const float* __restrict__ c3, const float* __restrict__ rs,
            short* __restrict__ z, float* __restrict__ aw0)
{
    __shared__ float t[32][33];
    const int w = blockIdx.y;
    const int tile = blockIdx.x;
    if (w == 8) {                       // zero aw accumulator
        int i = tile * 256 + threadIdx.y * 32 + threadIdx.x;
        if (i < N_ROWS) aw0[i] = 0.f;
        return;
    }
    const float* src; short* dst; int Kw, Nw;
    switch (w) {
        case 0: src = p1; dst = z + OFF_P1T;  Kw = 2048; Nw = 512; break;
        case 1: src = p2; dst = z + OFF_P2T;  Kw = 512;  Nw = 512; break;
        case 2: src = a1; dst = z + OFF_A1T;  Kw = 512;  Nw = 512; break;
        case 3: src = a2; dst = z + OFF_A2T;  Kw = 512;  Nw = 512; break;
        case 4: src = c1; dst = z + OFF_C1T;  Kw = 512;  Nw = 512; break;
        case 5: src = c2; dst = z + OFF_C2T;  Kw = 512;  Nw = 512; break;
        case 6: src = c3; dst = z + OFF_C3T;  Kw = 512;  Nw = 128; break;
        default: src = rs; dst = z + OFF_REST; Kw = 512; Nw = 128; break;
    }
    const int txc = Nw >> 5, tyc = Kw >> 5;
    if (tile >= txc * tyc) return;
    const int tc = tile % txc, tr = tile / txc;
    const int x = threadIdx.x, y = threadIdx.y;
    #pragma unroll
    for (int j = 0; j < 4; ++j)
        t[y + 8 * j][x] = src[(size_t)(tr * 32 + y + 8 * j) * Nw + tc * 32 + x];
    __syncthreads();
    #pragma unroll
    for (int j = 0; j < 4; ++j)
        dst[(size_t)(tc * 32 + y + 8 * j) * Kw + tr * 32 + x] = f2bf(t[x][y + 8 * j]);
}

// ---------------------------------------------------------------------------
// bf16 MFMA GEMM: BM=64, BN=128, BK=64, 256 thr = 4 waves (2x2), wave tile
// 32x64. A: [M][K] f32 (reg-staged) or bf16 (global_load_lds); B/B2: [N][K]
// bf16 k-major. LDS double-buffered, XOR-swizzled (both-sides rule); counted
// vmcnt (never 0 mid-loop) + raw s_barrier on the gload path. [R5-proven]
// ---------------------------------------------------------------------------
template<bool AF32, bool DUALB, int EPI, int KT>
__global__ __launch_bounds__(256)
void gemm(const void* __restrict__ Ap, const short* __restrict__ Bt,
          const short* __restrict__ Bt2,
          const float* __restrict__ bias, const float* __restrict__ bias2,
          const float* __restrict__ sb,
          const float* __restrict__ auxw, float* __restrict__ auxo,
          float* __restrict__ C, float* __restrict__ C2,
          short* __restrict__ Cb, int N)
{
    constexpr int NSTEP = KT / 64;
    constexpr int BROWS = DUALB ? 256 : 128;
    __shared__ short lds_a[2][64 * 64];
    __shared__ short lds_b[2][BROWS * 64];
    const int tid = threadIdx.x;
    // XCD-aware swizzle (nwg % 8 == 0 for all grids here)
    const int gx   = gridDim.x;
    const int orig = blockIdx.y * gx + blockIdx.x;
    const int cpx  = (gx * gridDim.y) >> 3;
    const int wg   = (orig & 7) * cpx + (orig >> 3);
    const int bx   = wg % gx;
    const int by   = wg / gx;
    const int row0 = by * 64;
    const int col0 = bx * 128;
    const int lane = tid & 63;
    const int wid  = tid >> 6;
    const int wm   = (wid >> 1) * 32;
    const int wn   = (wid & 1) * 64;
    const int l15  = lane & 15;
    const int lhi  = lane >> 4;

    f32x4 acc[2][4], acc2[2][4];
    #pragma unroll
    for (int i = 0; i < 2; ++i)
        #pragma unroll
        for (int j = 0; j < 4; ++j) {
            f32x4 z = {0.f, 0.f, 0.f, 0.f};
            acc[i][j] = z;
            if constexpr (DUALB) acc2[i][j] = z;
        }

    auto do_compute = [&](int p) {
        const short* la = lds_a[p];
        const short* lb = lds_b[p];
        #pragma unroll
        for (int kk = 0; kk < 2; ++kk) {
            bf16x8 af[2], bfr[4], bfr2[4];
            #pragma unroll
            for (int mi = 0; mi < 2; ++mi) {
                const int row = wm + mi * 16 + l15;
                af[mi] = *(const bf16x8*)(la + row * 64 + (((kk * 4 + lhi) ^ (row & 7)) << 3));
            }
            #pragma unroll
            for (int ni = 0; ni < 4; ++ni) {
                const int row = wn + ni * 16 + l15;
                bfr[ni] = *(const bf16x8*)(lb + row * 64 + (((kk * 4 + lhi) ^ (row & 7)) << 3));
                if constexpr (DUALB)
                    bfr2[ni] = *(const bf16x8*)(lb + (row + 128) * 64 + (((kk * 4 + lhi) ^ (row & 7)) << 3));
            }
            #pragma unroll
            for (int mi = 0; mi < 2; ++mi)
                #pragma unroll
                for (int ni = 0; ni < 4; ++ni) {
                    acc[mi][ni] = __builtin_amdgcn_mfma_f32_16x16x32_bf16(
                        af[mi], bfr[ni], acc[mi][ni], 0, 0, 0);
                    if constexpr (DUALB)
                        acc2[mi][ni] = __builtin_amdgcn_mfma_f32_16x16x32_bf16(
                            af[mi], bfr2[ni], acc2[mi][ni], 0, 0, 0);
                }
        }
    };

    if constexpr (!AF32) {
        // ---- async gload_lds path (A is bf16 k-major) ----
        auto stage = [&](int p, int kt) {
            #pragma unroll
            for (int i = 0; i < 2; ++i) {
                const int q = tid + (i << 8);
                const int r = q >> 3, c16 = q & 7;
                GLOAD16((const short*)Ap + (size_t)(row0 + r) * KT + kt + ((c16 ^ (r & 7)) << 3),
                        lds_a[p] + (i << 11) + (wid << 9));
            }
            #pragma unroll
            for (int i = 0; i < 4; ++i) {
                const int q = tid + (i << 8);
                const int r = q >> 3, c16 = q & 7;
                GLOAD16(Bt + (size_t)(col0 + r) * KT + kt + ((c16 ^ (r & 7)) << 3),
                        lds_b[p] + (i << 11) + (wid << 9));
                if constexpr (DUALB)
                    GLOAD16(Bt2 + (size_t)(col0 + r) * KT + kt + ((c16 ^ (r & 7)) << 3),
                            lds_b[p] + 8192 + (i << 11) + (wid << 9));
            }
        };
        stage(0, 0);
        if (NSTEP > 1) stage(1, 64);
        for (int s = 0; s < NSTEP; ++s) {
            if (s + 1 < NSTEP) {            // tile s done; tile s+1 stays in flight
                if constexpr (DUALB) asm volatile("s_waitcnt vmcnt(10)" ::: "memory");
                else                 asm volatile("s_waitcnt vmcnt(6)"  ::: "memory");
            } else {
                asm volatile("s_waitcnt vmcnt(0)" ::: "memory");
            }
            __builtin_amdgcn_s_barrier();           // all waves' tile-s parts done
            __builtin_amdgcn_sched_barrier(0);
            do_compute(s & 1);
            __builtin_amdgcn_s_barrier();           // all done reading buf[s&1]
            __builtin_amdgcn_sched_barrier(0);
            if (s + 2 < NSTEP) stage(s & 1, (s + 2) * 64);
        }
    } else {
        // ---- reg-staged path (A is f32, converted in flight) ----
        bf16x8 ra[2], rb[4];
        auto load_a = [&](int kt) {
            #pragma unroll
            for (int i = 0; i < 2; ++i) {
                const int q = tid + (i << 8);
                const int r = q >> 3, c16 = q & 7;
                const float* p = (const float*)Ap + (size_t)(row0 + r) * KT + kt + c16 * 8;
                float4 u0 = *(const float4*)p;
                float4 u1 = *(const float4*)(p + 4);
                bf16x8 v;
                v[0] = f2bf(u0.x); v[1] = f2bf(u0.y); v[2] = f2bf(u0.z); v[3] = f2bf(u0.w);
                v[4] = f2bf(u1.x); v[5] = f2bf(u1.y); v[6] = f2bf(u1.z); v[7] = f2bf(u1.w);
                ra[i] = v;
            }
        };
        auto load_b = [&](int kt) {
            #pragma unroll
            for (int i = 0; i < 4; ++i) {
                const int q = tid + (i << 8);
                const int r = q >> 3, c16 = q & 7;
                rb[i] = *(const bf16x8*)(Bt + (size_t)(col0 + r) * KT + kt + c16 * 8);
            }
        };
        auto write_tile = [&](int p) {
            #pragma unroll
            for (int i = 0; i < 2; ++i) {
                const int q = tid + (i << 8);
                const int r = q >> 3, c16 = q & 7;
                *(bf16x8*)(lds_a[p] + r * 64 + ((c16 ^ (r & 7)) << 3)) = ra[i];
            }
            #pragma unroll
            for (int i = 0; i < 4; ++i) {
                const int q = tid + (i << 8);
                const int r = q >> 3, c16 = q & 7;
                *(bf16x8*)(lds_b[p] + r * 64 + ((c16 ^ (r & 7)) << 3)) = rb[i];
            }
        };
        load_a(0); load_b(0);
        write_tile(0);
        if (NSTEP > 1) { load_a(64); load_b(64); }
        #pragma unroll 2
        for (int s = 0; s < NSTEP; ++s) {
            __syncthreads();
            do_compute(s & 1);
            if (s + 1 < NSTEP) {
                write_tile((s + 1) & 1);
                if (s + 2 < NSTEP) { load_a((s + 2) * 64); load_b((s + 2) * 64); }
            }
        }
    }

    // epilogues: C/D row=(lane>>4)*4+j, col=lane&15 [verified rounds 1-7]
    if constexpr (EPI == EPI_A12) {
        float pd[2][4];
        #pragma unroll
        for (int mi = 0; mi < 2; ++mi)
            #pragma unroll
            for (int j = 0; j < 4; ++j) pd[mi][j] = 0.f;
        #pragma unroll
        for (int mi = 0; mi < 2; ++mi)
            #pragma unroll
            for (int ni = 0; ni < 4; ++ni) {
                const int col = col0 + wn + ni * 16 + l15;
                const float b1 = bias[col], b2 = bias2[col], w3 = auxw[col];
                #pragma unroll
                for (int j = 0; j < 4; ++j) {
                    float g1 = 1.f / (1.f + expf(-(acc[mi][ni][j] + b1)));
                    float g2 = tanhf(acc2[mi][ni][j] + b2);
                    pd[mi][j] += g1 * g2 * w3;
                }
            }
        #pragma unroll
        for (int mi = 0; mi < 2; ++mi)
            #pragma unroll
            for (int j = 0; j < 4; ++j) {
                float v = pd[mi][j];
                v += __shfl_xor(v, 1); v += __shfl_xor(v, 2);
                v += __shfl_xor(v, 4); v += __shfl_xor(v, 8);
                if (l15 == 0) {
                    if (bx == 0 && wn == 0) v += sb[0];   // fold a3_b exactly once/row
                    atomicAdd(&auxo[row0 + wm + mi * 16 + lhi * 4 + j], v);
                }
            }
    } else if constexpr (EPI == EPI_ZW) {
        // Cb = bf16(acc); t[col] += sum_rows u[row]*acc  (colsum fused, fp32-exact)
        float ur[2][4];
        #pragma unroll
        for (int mi = 0; mi < 2; ++mi)
            #pragma unroll
            for (int j = 0; j < 4; ++j)
                ur[mi][j] = auxw[row0 + wm + mi * 16 + lhi * 4 + j];
        float tp[4] = {0.f, 0.f, 0.f, 0.f};
        #pragma unroll
        for (int mi = 0; mi < 2; ++mi)
            #pragma unroll
            for (int ni = 0; ni < 4; ++ni) {
                const int col = col0 + wn + ni * 16 + l15;
                #pragma unroll
                for (int j = 0; j < 4; ++j) {
                    const int row = row0 + wm + mi * 16 + lhi * 4 + j;
                    const float val = acc[mi][ni][j];
                    Cb[(size_t)row * N + col] = f2bf(val);
                    tp[ni] += ur[mi][j] * val;
                }
            }
        #pragma unroll
        for (int ni = 0; ni < 4; ++ni) {
            float v = tp[ni];
            v += __shfl_xor(v, 16); v += __shfl_xor(v, 32);
            if (lhi == 0)
                atomicAdd(&auxo[col0 + wn + ni * 16 + l15], v);
        }
    } else if constexpr (EPI == EPI_C3RES) {
        if (bx == 0) {
            float ur[2][4];
            #pragma unroll
            for (int mi = 0; mi < 2; ++mi)
                #pragma unroll
                for (int j = 0; j < 4; ++j)
                    ur[mi][j] = auxw[row0 + wm + mi * 16 + lhi * 4 + j];
            float tp[4] = {0.f, 0.f, 0.f, 0.f};
            #pragma unroll
            for (int mi = 0; mi < 2; ++mi)
                #pragma unroll
                for (int ni = 0; ni < 4; ++ni) {
                    const int c = wn + ni * 16 + l15;
                    #pragma unroll
                    for (int j = 0; j < 4; ++j) {
                        const int row = row0 + wm + mi * 16 + lhi * 4 + j;
                        const float val = acc[mi][ni][j];
                        C[(size_t)row * D_OUTF + c] = val;
                        tp[ni] += ur[mi][j] * val;
                    }
                }
            #pragma unroll
            for (int ni = 0; ni < 4; ++ni) {
                float v = tp[ni];
                v += __shfl_xor(v, 16); v += __shfl_xor(v, 32);
                if (lhi == 0)
                    atomicAdd(&auxo[wn + ni * 16 + l15], v);
            }
        } else {
            #pragma unroll
            for (int mi = 0; mi < 2; ++mi)
                #pragma unroll
                for (int ni = 0; ni < 4; ++ni) {
                    const int c = wn + ni * 16 + l15;
                    #pragma unroll
                    for (int j = 0; j < 4; ++j) {
                        const int row = row0 + wm + mi * 16 + lhi * 4 + j;
                        C2[(size_t)row * D_OUTF + c] = acc[mi][ni][j] + bias[c];
                    }
                }
        }
    } else {
        #pragma unroll
        for (int mi = 0; mi < 2; ++mi)
            #pragma unroll
            for (int ni = 0; ni < 4; ++ni) {
                const int col = col0 + wn + ni * 16 + l15;
                #pragma unroll
                for (int j = 0; j < 4; ++j) {
                    const int row = row0 + wm + mi * 16 + lhi * 4 + j;
                    float val = acc[mi][ni][j] + bias[col];
                    if constexpr (EPI == EPI_H0B) val = fmaxf(val, 0.f);
                    Cb[(size_t)row * N + col] = f2bf(val);
                }
            }
    }
}

// ---------------------------------------------------------------------------
template<int NT>
__device__ __forceinline__ void block_reduce2(float& s, float& s2)
{
    #pragma unroll
    for (int o = 32; o > 0; o >>= 1) {
        s  += __shfl_down(s,  o);
        s2 += __shfl_down(s2, o);
    }
    __shared__ float sm[2][NT / 64];
    const int wid  = threadIdx.x >> 6;
    const int lane = threadIdx.x & 63;
    if (lane == 0) { sm[0][wid] = s; sm[1][wid] = s2; }
    __syncthreads();
    float a = 0.f, b = 0.f;
    #pragma unroll
    for (int w = 0; w < NT / 64; ++w) { a += sm[0][w]; b += sm[1][w]; }
    s = a; s2 = b;
}

// LayerNorm, wave-per-row (4 rows/block, shfl-only): bf16 in -> bf16 out
__global__ __launch_bounds__(256)
void ln_b(const short* __restrict__ in, const float* __restrict__ g,
          const float* __restrict__ b, short* __restrict__ out)
{
    const int row  = blockIdx.x * 4 + (threadIdx.x >> 6);
    const int lane = threadIdx.x & 63;
    const int c0   = lane * 8;
    bf16x8 h8 = *(const bf16x8*)(in + (size_t)row * D_H + c0);
    float v[8], s = 0.f, s2 = 0.f;
    #pragma unroll
    for (int i = 0; i < 8; ++i) { v[i] = bf2f(h8[i]); s += v[i]; s2 += v[i] * v[i]; }
    #pragma unroll
    for (int o = 1; o < 64; o <<= 1) { s += __shfl_xor(s, o); s2 += __shfl_xor(s2, o); }
    const float mean = s * (1.f / D_H);
    const float rs   = rsqrtf(s2 * (1.f / D_H) - mean * mean + 1e-5f);
    float ga[8], ba[8];
    *(float4*)ga       = *(const float4*)(g + c0);
    *(float4*)(ga + 4) = *(const float4*)(g + c0 + 4);
    *(float4*)ba       = *(const float4*)(b + c0);
    *(float4*)(ba + 4) = *(const float4*)(b + c0 + 4);
    bf16x8 o8;
    #pragma unroll
    for (int i = 0; i < 8; ++i) o8[i] = f2bf((v[i] - mean) * rs * ga[i] + ba[i]);
    *(bf16x8*)(out + (size_t)row * D_H + c0) = o8;
}

// x_next = LN(relu(u_i*t + v_i*zw_i + cb))*g + b + resid ; wave-per-row, bf16
__global__ __launch_bounds__(256)
void fuse_b(const short* __restrict__ zw, const float* __restrict__ t,
            const float* __restrict__ u, const float* __restrict__ vv,
            const float* __restrict__ cb, const float* __restrict__ g,
            const float* __restrict__ b, const short* __restrict__ resid,
            short* __restrict__ out)
{
    const int row  = blockIdx.x * 4 + (threadIdx.x >> 6);
    const int lane = threadIdx.x & 63;
    const int c0   = lane * 8;
    const float ui = u[row], vi = vv[row];
    bf16x8 z8 = *(const bf16x8*)(zw + (size_t)row * D_H + c0);
    float ta[8], ca[8];
    *(float4*)ta       = *(const float4*)(t + c0);
    *(float4*)(ta + 4) = *(const float4*)(t + c0 + 4);
    *(float4*)ca       = *(const float4*)(cb + c0);
    *(float4*)(ca + 4) = *(const float4*)(cb + c0 + 4);
    float y[8], s = 0.f, s2 = 0.f;
    #pragma unroll
    for (int i = 0; i < 8; ++i) {
        float val = fmaxf(ui * ta[i] + vi * bf2f(z8[i]) + ca[i], 0.f);
        y[i] = val; s += val; s2 += val * val;
    }
    #pragma unroll
    for (int o = 1; o < 64; o <<= 1) { s += __shfl_xor(s, o); s2 += __shfl_xor(s2, o); }
    const float mean = s * (1.f / D_H);
    const float rs   = rsqrtf(s2 * (1.f / D_H) - mean * mean + 1e-5f);
    bf16x8 r8 = *(const bf16x8*)(resid + (size_t)row * D_H + c0);
    float ga[8], ba[8];
    *(float4*)ga       = *(const float4*)(g + c0);
    *(float4*)(ga + 4) = *(const float4*)(g + c0 + 4);
    *(float4*)ba       = *(const float4*)(b + c0);
    *(float4*)(ba + 4) = *(const float4*)(b + c0 + 4);
    bf16x8 o8;
    #pragma unroll
    for (int i = 0; i < 8; ++i)
        o8[i] = f2bf((y[i] - mean) * rs * ga[i] + ba[i] + bf2f(r8[i]));
    *(bf16x8*)(out + (size_t)row * D_H + c0) = o8;
}

// s = sigmoid(aw); S = sum(s); u = s*dinv; v = dinv^2*(1-s^2); zero t1..t3
__global__ __launch_bounds__(1024)
void prep(const float* __restrict__ aw, float* __restrict__ s_out,
          float* __restrict__ u, float* __restrict__ v,
          float* __restrict__ t1, float* __restrict__ t2, float* __restrict__ t3)
{
    const int tid = threadIdx.x;
    float acc = 0.f;
    for (int i = tid; i < N_ROWS; i += 1024) {
        float si = 1.f / (1.f + expf(-aw[i]));
        s_out[i] = si;
        acc += si;
    }
    float dummy = 0.f;
    block_reduce2<1024>(acc, dummy);
    const float S = acc;
    for (int i = tid; i < N_ROWS; i += 1024) {
        float si   = s_out[i];
        float dinv = rsqrtf(1.f + si * (S - si));   // deg = 1 + s_i*(S - s_i)
        u[i] = si * dinv;
        v[i] = dinv * dinv * (1.f - si * si);
    }
    if (tid < D_H)   { t1[tid] = 0.f; t2[tid] = 0.f; }
    if (tid < D_OUTF)  t3[tid] = 0.f;
}

// ---------------------------------------------------------------------------
// tail: blocks 0..2047 layer-3 fuse; blocks 2048..4095 write the full mam
// (268 MB streaming; scratch in the mam region is dead by stream order).
// ---------------------------------------------------------------------------
__global__ __launch_bounds__(256)
void tail(const float* __restrict__ zw, const float* __restrict__ t,
          const float* __restrict__ u, const float* __restrict__ vv,
          const float* __restrict__ cb, const float* __restrict__ g,
          const float* __restrict__ b, const float* __restrict__ resid,
          float* __restrict__ out,
          const float* __restrict__ s, float* __restrict__ mam_out)
{
    if (blockIdx.x < 2048) {
        const int row  = blockIdx.x * 4 + (threadIdx.x >> 6);
        const int lane = threadIdx.x & 63;
        const int c0   = lane * 2;
        const float ui = u[row], vi = vv[row];
        float2 z2 = *(const float2*)(zw + (size_t)row * D_OUTF + c0);
        float y0 = fmaxf(ui * t[c0]     + vi * z2.x + cb[c0],     0.f);
        float y1 = fmaxf(ui * t[c0 + 1] + vi * z2.y + cb[c0 + 1], 0.f);
        float sr = y0 + y1, s2 = y0 * y0 + y1 * y1;
        #pragma unroll
        for (int o = 1; o < 64; o <<= 1) { sr += __shfl_xor(sr, o); s2 += __shfl_xor(s2, o); }
        const float mean = sr * (1.f / D_OUTF);
        const float rs   = rsqrtf(s2 * (1.f / D_OUTF) - mean * mean + 1e-5f);
        float2 r2 = *(const float2*)(resid + (size_t)row * D_OUTF + c0);
        float2 o2;
        o2.x = (y0 - mean) * rs * g[c0]     + b[c0]     + r2.x;
        o2.y = (y1 - mean) * rs * g[c0 + 1] + b[c0 + 1] + r2.y;
        *(float2*)(out + (size_t)row * D_OUTF + c0) = o2;
        return;
    }
    const int mb = blockIdx.x - 2048;
    const f32x4* s4 = (const f32x4*)s;
    const size_t total  = (size_t)N_ROWS * 2048;
    const size_t stride = (size_t)2048 * 256;
    for (size_t gg = (size_t)mb * 256 + threadIdx.x; gg < total; gg += stride) {
        const int row = (int)(gg >> 11);
        const int c4  = (int)(gg & 2047);
        f32x4 o = s[row] * s4[c4];
        __builtin_nontemporal_store(o, (f32x4*)(mam_out + ((size_t)row << 13) + ((size_t)c4 << 2)));
    }
}

// ---------------------------------------------------------------------------
// ws: h0b bf16 8MB | zwb bf16 8MB | zw3 4MB | resb 4MB | smalls. Weights and
// slot1/slot2 live in the mam output region, rewritten by tail at the end.
// ---------------------------------------------------------------------------
extern "C" void kernel_launch(void* const* d_in, const int* in_sizes, int n_in,
                              void* d_out, int out_size, void* d_ws, size_t ws_size,
                              hipStream_t stream)
{
    const float* x     = (const float*)d_in[0];
    const float* p1_w  = (const float*)d_in[1];
    const float* p1_b  = (const float*)d_in[2];
    const float* ln0_g = (const float*)d_in[3];
    const float* ln0_b = (const float*)d_in[4];
    const float* p2_w  = (const float*)d_in[5];
    const float* p2_b  = (const float*)d_in[6];
    const float* a1_w  = (const float*)d_in[7];
    const float* a1_b  = (const float*)d_in[8];
    const float* a2_w  = (const float*)d_in[9];
    const float* a2_b  = (const float*)d_in[10];
    const float* a3_w  = (const float*)d_in[11];
    const float* a3_b  = (const float*)d_in[12];
    const float* c1_w  = (const float*)d_in[13];
    const float* c1_b  = (const float*)d_in[14];
    const float* ln1_g = (const float*)d_in[15];
    const float* ln1_b = (const float*)d_in[16];
    const float* c2_w  = (const float*)d_in[17];
    const float* c2_b  = (const float*)d_in[18];
    const float* ln2_g = (const float*)d_in[19];
    const float* ln2_b = (const float*)d_in[20];
    const float* c3_w  = (const float*)d_in[21];
    const float* c3_b  = (const float*)d_in[22];
    const float* ln3_g = (const float*)d_in[23];
    const float* ln3_b = (const float*)d_in[24];
    const float* res_w = (const float*)d_in[25];
    const float* res_b = (const float*)d_in[26];

    float* ws   = (float*)d_ws;
    short* wsS  = (short*)d_ws;
    short* h0b  = wsS;                                 // bf16 [8192][512]
    short* zwb  = wsS + (size_t)N_ROWS * D_H;          // bf16 [8192][512]
    float* wsF  = ws + (size_t)N_ROWS * D_H / 2 * 2;   // after the two bf16 slots
    float* zw3  = wsF;                                 // [8192][128] f32
    float* resb = zw3 + (size_t)N_ROWS * D_OUTF;       // [8192][128] f32
    float* s_buf = resb + (size_t)N_ROWS * D_OUTF;
    float* u_buf = s_buf + N_ROWS;
    float* v_buf = u_buf + N_ROWS;
    float* t1    = v_buf + N_ROWS;
    float* t2    = t1 + D_H;
    float* t3    = t2 + D_H;

    float* out_x3  = (float*)d_out;
    float* out_aw  = out_x3 + (size_t)N_ROWS * D_OUTF;
    float* out_mam = out_aw + N_ROWS;
    short* Z     = (short*)out_mam;                    // scratch in mam region
    short* slot1 = Z + OFF_SLOT1;                      // h_ln -> x1
    short* slot2 = Z + OFF_SLOT2;                      // h    -> x2

    dim3 blk(256);
    dim3 tb(32, 8);
    dim3 gP(4, 128);     // 512 blocks
    dim3 gC(2, 128);     // 256 blocks

    wtrans<<<dim3(1024, 9), tb, 0, stream>>>(p1_w, p2_w, a1_w, a2_w, c1_w, c2_w, c3_w, res_w, Z, out_aw);

    // projection (reg-staged f32 A path)
    gemm<true,  false, EPI_H0B,   D_IN><<<gP, blk, 0, stream>>>(
        x, Z + OFF_P1T, nullptr, p1_b, nullptr, nullptr, nullptr, nullptr, nullptr, nullptr, h0b, D_H);
    ln_b<<<2048, 256, 0, stream>>>(h0b, ln0_g, ln0_b, slot1);
    gemm<false, false, EPI_BIASB, D_H><<<gP, blk, 0, stream>>>(
        slot1, Z + OFF_P2T, nullptr, p2_b, nullptr, nullptr, nullptr, nullptr, nullptr, nullptr, slot2, D_H);
    // attention gate: aw = (sigmoid(h@a1+b1)*tanh(h@a2+b2))@a3_w + a3_b
    gemm<false, true,  EPI_A12,   D_H><<<gP, blk, 0, stream>>>(
        slot2, Z + OFF_A1T, Z + OFF_A2T, a1_b, a2_b, a3_b, a3_w, out_aw, nullptr, nullptr, nullptr, D_H);
    prep<<<1, 1024, 0, stream>>>(out_aw, s_buf, u_buf, v_buf, t1, t2, t3);
    // GCN layer 1
    gemm<false, false, EPI_ZW,    D_H><<<gP, blk, 0, stream>>>(
        slot2, Z + OFF_C1T, nullptr, nullptr, nullptr, nullptr, u_buf, t1, nullptr, nullptr, zwb, D_H);
    fuse_b<<<2048, 256, 0, stream>>>(zwb, t1, u_buf, v_buf, c1_b, ln1_g, ln1_b, slot2, slot1);
    // GCN layer 2
    gemm<false, false, EPI_ZW,    D_H><<<gP, blk, 0, stream>>>(
        slot1, Z + OFF_C2T, nullptr, nullptr, nullptr, nullptr, u_buf, t2, nullptr, nullptr, zwb, D_H);
    fuse_b<<<2048, 256, 0, stream>>>(zwb, t2, u_buf, v_buf, c2_b, ln2_g, ln2_b, slot1, slot2);
    // GCN layer 3 + residual projection (fused N=256 GEMM, colsum fused)
    gemm<false, false, EPI_C3RES, D_H><<<gC, blk, 0, stream>>>(
        slot2, Z + OFF_C3T, nullptr, res_b, nullptr, nullptr, u_buf, t3, zw3, resb, nullptr, 256);
    // layer-3 fuse + full mam write (mam-region scratch dead by stream order)
    tail<<<4096, 256, 0, stream>>>(zw3, t3, u_buf, v_buf, c3_b, ln3_g, ln3_b, resb, out_x3,
                                   s_buf, out_mam);
}